// Round 1
// baseline (385.574 us; speedup 1.0000x reference)
//
#include <hip/hip_runtime.h>
#include <math.h>

#define B 64
#define K 5
#define D 1024
#define H 32
#define W 32
#define N (H * W)

__device__ __forceinline__ float wave_sum(float v) {
#pragma unroll
    for (int off = 32; off > 0; off >>= 1) v += __shfl_down(v, off, 64);
    return v;
}

// One block per cue row (b*K+k). 256 threads x float4 covers D=1024.
__global__ __launch_bounds__(256) void normalize_cue(const float* __restrict__ cue,
                                                     float* __restrict__ cue_n) {
    const int row = blockIdx.x;
    const int tid = threadIdx.x;
    const float4* src = (const float4*)(cue + (size_t)row * D);
    float4 p = src[tid];
    float ss = p.x * p.x + p.y * p.y + p.z * p.z + p.w * p.w;
    ss = wave_sum(ss);
    __shared__ float smem[4];
    __shared__ float s_inv;
    const int lane = tid & 63, wid = tid >> 6;
    if (lane == 0) smem[wid] = ss;
    __syncthreads();
    if (tid == 0) {
        float t = smem[0] + smem[1] + smem[2] + smem[3];
        s_inv = 1.0f / fmaxf(sqrtf(t), 1e-12f);
    }
    __syncthreads();
    const float inv = s_inv;
    float4 o = make_float4(p.x * inv, p.y * inv, p.z * inv, p.w * inv);
    ((float4*)(cue_n + (size_t)row * D))[tid] = o;
}

// One block per (b, n). Loads the 4KB patch row once (the big HBM pass),
// computes ||p||^2 and 5 dots against L1-resident cue_n rows.
__global__ __launch_bounds__(256) void sims_kernel(const float* __restrict__ patches,
                                                   const float* __restrict__ cue_n,
                                                   float* __restrict__ sims) {
    const int bn = blockIdx.x;  // b*N + n
    const int b = bn >> 10;
    const int n = bn & (N - 1);
    const int tid = threadIdx.x;

    const float4* prow = (const float4*)(patches + (size_t)bn * D);
    float4 p = prow[tid];

    float acc[1 + K];
    acc[0] = p.x * p.x + p.y * p.y + p.z * p.z + p.w * p.w;
    const float4* crow = (const float4*)(cue_n + (size_t)b * K * D);
#pragma unroll
    for (int k = 0; k < K; ++k) {
        float4 c = crow[(size_t)k * (D / 4) + tid];
        acc[1 + k] = p.x * c.x + p.y * c.y + p.z * c.z + p.w * c.w;
    }

    const int lane = tid & 63, wid = tid >> 6;
    __shared__ float smem[4][1 + K];
#pragma unroll
    for (int j = 0; j < 1 + K; ++j) {
        float v = wave_sum(acc[j]);
        if (lane == 0) smem[wid][j] = v;
    }
    __syncthreads();
    if (tid == 0) {
        float t[1 + K];
#pragma unroll
        for (int j = 0; j < 1 + K; ++j)
            t[j] = smem[0][j] + smem[1][j] + smem[2][j] + smem[3][j];
        const float inv = 1.0f / fmaxf(sqrtf(t[0]), 1e-12f);
#pragma unroll
        for (int k = 0; k < K; ++k)
            sims[((size_t)b * K + k) * N + n] = t[1 + k] * inv;
    }
}

// One block per (b, k): argmax over N sims (first-index tie-break),
// then mean of raw patches over the 3x3 zero-padded neighborhood.
__global__ __launch_bounds__(256) void argmax_gather(const float* __restrict__ sims,
                                                     const float* __restrict__ patches,
                                                     float* __restrict__ out) {
    const int row = blockIdx.x;  // b*K + k
    const int b = row / K;
    const int tid = threadIdx.x;

    const float* srow = sims + (size_t)row * N;
    float best = -INFINITY;
    int bidx = 0;
#pragma unroll
    for (int j = 0; j < 4; ++j) {
        const int d = tid * 4 + j;
        const float v = srow[d];
        if (v > best) { best = v; bidx = d; }
    }
#pragma unroll
    for (int off = 32; off > 0; off >>= 1) {
        const float ov = __shfl_down(best, off, 64);
        const int oi = __shfl_down(bidx, off, 64);
        if (ov > best || (ov == best && oi < bidx)) { best = ov; bidx = oi; }
    }
    __shared__ float sv[4];
    __shared__ int si[4];
    __shared__ int s_final;
    const int lane = tid & 63, wid = tid >> 6;
    if (lane == 0) { sv[wid] = best; si[wid] = bidx; }
    __syncthreads();
    if (tid == 0) {
        float bv = sv[0];
        int bi = si[0];
        for (int w2 = 1; w2 < 4; ++w2) {
            if (sv[w2] > bv || (sv[w2] == bv && si[w2] < bi)) { bv = sv[w2]; bi = si[w2]; }
        }
        s_final = bi;
    }
    __syncthreads();

    const int idx = s_final;
    const int y0 = idx >> 5;   // idx / W
    const int x0 = idx & 31;   // idx % W

    float4 acc = make_float4(0.f, 0.f, 0.f, 0.f);
#pragma unroll
    for (int dy = -1; dy <= 1; ++dy) {
        const int yy = y0 + dy;
        if (yy < 0 || yy >= H) continue;
#pragma unroll
        for (int dx = -1; dx <= 1; ++dx) {
            const int xx = x0 + dx;
            if (xx < 0 || xx >= W) continue;
            const float4* nrow =
                (const float4*)(patches + (((size_t)b * H + yy) * W + xx) * D);
            float4 p = nrow[tid];
            acc.x += p.x; acc.y += p.y; acc.z += p.z; acc.w += p.w;
        }
    }
    const float inv9 = 1.0f / 9.0f;
    float4 o = make_float4(acc.x * inv9, acc.y * inv9, acc.z * inv9, acc.w * inv9);
    ((float4*)(out + (size_t)row * D))[tid] = o;
}

extern "C" void kernel_launch(void* const* d_in, const int* in_sizes, int n_in,
                              void* d_out, int out_size, void* d_ws, size_t ws_size,
                              hipStream_t stream) {
    const float* cue = (const float*)d_in[0];
    const float* patches = (const float*)d_in[1];
    float* out = (float*)d_out;

    float* cue_n = (float*)d_ws;            // B*K*D floats = 1.25 MiB
    float* sims = cue_n + (size_t)B * K * D;  // B*K*N floats = 1.25 MiB

    normalize_cue<<<B * K, 256, 0, stream>>>(cue, cue_n);
    sims_kernel<<<B * N, 256, 0, stream>>>(patches, cue_n, sims);
    argmax_gather<<<B * K, 256, 0, stream>>>(sims, patches, out);
}

// Round 2
// 364.860 us; speedup vs baseline: 1.0568x; 1.0568x over previous
//
#include <hip/hip_runtime.h>
#include <math.h>

#define B 64
#define K 5
#define D 1024
#define H 32
#define W 32
#define N (H * W)

__device__ __forceinline__ float wave_sum(float v) {
#pragma unroll
    for (int off = 32; off > 0; off >>= 1) v += __shfl_down(v, off, 64);
    return v;
}

__device__ __forceinline__ float dot4(float4 a, float4 b) {
    return a.x * b.x + a.y * b.y + a.z * b.z + a.w * b.w;
}

// One block per cue row (b*K+k). 256 threads x float4 covers D=1024.
__global__ __launch_bounds__(256) void normalize_cue(const float* __restrict__ cue,
                                                     float* __restrict__ cue_n) {
    const int row = blockIdx.x;
    const int tid = threadIdx.x;
    const float4* src = (const float4*)(cue + (size_t)row * D);
    float4 p = src[tid];
    float ss = p.x * p.x + p.y * p.y + p.z * p.z + p.w * p.w;
    ss = wave_sum(ss);
    __shared__ float smem[4];
    __shared__ float s_inv;
    const int lane = tid & 63, wid = tid >> 6;
    if (lane == 0) smem[wid] = ss;
    __syncthreads();
    if (tid == 0) {
        float t = smem[0] + smem[1] + smem[2] + smem[3];
        s_inv = 1.0f / fmaxf(sqrtf(t), 1e-12f);
    }
    __syncthreads();
    const float inv = s_inv;
    float4 o = make_float4(p.x * inv, p.y * inv, p.z * inv, p.w * inv);
    ((float4*)(cue_n + (size_t)row * D))[tid] = o;
}

// One WAVE per 2 patch rows. Block = 4 waves = 8 rows. Grid = B*N/8 blocks.
// Each lane accumulates 16 elems/row via 4 coalesced float4 loads; cue is
// loaded once per wave and reused for both rows (halves cue L2 traffic).
// Reduction: 12 values x 6 butterfly steps per wave (36 DS ops per row,
// was 144) keeps the DS pipe under the HBM stream time.
__global__ __launch_bounds__(256) void sims_kernel(const float* __restrict__ patches,
                                                   const float* __restrict__ cue_n,
                                                   float* __restrict__ sims) {
    const int wave = threadIdx.x >> 6;
    const int lane = threadIdx.x & 63;
    const int bn0 = blockIdx.x * 8 + wave * 2;  // global row index, 8 | N so b uniform
    const int b = bn0 >> 10;
    const int n0 = bn0 & (N - 1);

    const float4* p0 = (const float4*)(patches + (size_t)bn0 * D);
    const float4* p1 = (const float4*)(patches + (size_t)(bn0 + 1) * D);
    const float4* crow = (const float4*)(cue_n + (size_t)b * K * D);

    float na = 0.f, nb = 0.f;
    float da[K], db[K];
#pragma unroll
    for (int k = 0; k < K; ++k) { da[k] = 0.f; db[k] = 0.f; }

#pragma unroll
    for (int j = 0; j < 4; ++j) {
        const int idx = j * 64 + lane;  // float4 index within the 256-float4 row
        float4 pa = p0[idx];
        float4 pb = p1[idx];
        na += dot4(pa, pa);
        nb += dot4(pb, pb);
#pragma unroll
        for (int k = 0; k < K; ++k) {
            float4 c = crow[(size_t)k * (D / 4) + idx];
            da[k] += dot4(pa, c);
            db[k] += dot4(pb, c);
        }
    }

    na = wave_sum(na);
    nb = wave_sum(nb);
#pragma unroll
    for (int k = 0; k < K; ++k) {
        da[k] = wave_sum(da[k]);
        db[k] = wave_sum(db[k]);
    }

    if (lane == 0) {
        const float ia = 1.0f / fmaxf(sqrtf(na), 1e-12f);
        const float ib = 1.0f / fmaxf(sqrtf(nb), 1e-12f);
#pragma unroll
        for (int k = 0; k < K; ++k) {
            sims[((size_t)b * K + k) * N + n0] = da[k] * ia;
            sims[((size_t)b * K + k) * N + n0 + 1] = db[k] * ib;
        }
    }
}

// One block per (b, k): argmax over N sims (first-index tie-break),
// then mean of raw patches over the 3x3 zero-padded neighborhood.
__global__ __launch_bounds__(256) void argmax_gather(const float* __restrict__ sims,
                                                     const float* __restrict__ patches,
                                                     float* __restrict__ out) {
    const int row = blockIdx.x;  // b*K + k
    const int b = row / K;
    const int tid = threadIdx.x;

    const float* srow = sims + (size_t)row * N;
    float best = -INFINITY;
    int bidx = 0;
#pragma unroll
    for (int j = 0; j < 4; ++j) {
        const int d = tid * 4 + j;
        const float v = srow[d];
        if (v > best) { best = v; bidx = d; }
    }
#pragma unroll
    for (int off = 32; off > 0; off >>= 1) {
        const float ov = __shfl_down(best, off, 64);
        const int oi = __shfl_down(bidx, off, 64);
        if (ov > best || (ov == best && oi < bidx)) { best = ov; bidx = oi; }
    }
    __shared__ float sv[4];
    __shared__ int si[4];
    __shared__ int s_final;
    const int lane = tid & 63, wid = tid >> 6;
    if (lane == 0) { sv[wid] = best; si[wid] = bidx; }
    __syncthreads();
    if (tid == 0) {
        float bv = sv[0];
        int bi = si[0];
        for (int w2 = 1; w2 < 4; ++w2) {
            if (sv[w2] > bv || (sv[w2] == bv && si[w2] < bi)) { bv = sv[w2]; bi = si[w2]; }
        }
        s_final = bi;
    }
    __syncthreads();

    const int idx = s_final;
    const int y0 = idx >> 5;   // idx / W
    const int x0 = idx & 31;   // idx % W

    float4 acc = make_float4(0.f, 0.f, 0.f, 0.f);
#pragma unroll
    for (int dy = -1; dy <= 1; ++dy) {
        const int yy = y0 + dy;
        if (yy < 0 || yy >= H) continue;
#pragma unroll
        for (int dx = -1; dx <= 1; ++dx) {
            const int xx = x0 + dx;
            if (xx < 0 || xx >= W) continue;
            const float4* nrow =
                (const float4*)(patches + (((size_t)b * H + yy) * W + xx) * D);
            float4 p = nrow[tid];
            acc.x += p.x; acc.y += p.y; acc.z += p.z; acc.w += p.w;
        }
    }
    const float inv9 = 1.0f / 9.0f;
    float4 o = make_float4(acc.x * inv9, acc.y * inv9, acc.z * inv9, acc.w * inv9);
    ((float4*)(out + (size_t)row * D))[tid] = o;
}

extern "C" void kernel_launch(void* const* d_in, const int* in_sizes, int n_in,
                              void* d_out, int out_size, void* d_ws, size_t ws_size,
                              hipStream_t stream) {
    const float* cue = (const float*)d_in[0];
    const float* patches = (const float*)d_in[1];
    float* out = (float*)d_out;

    float* cue_n = (float*)d_ws;              // B*K*D floats = 1.25 MiB
    float* sims = cue_n + (size_t)B * K * D;  // B*K*N floats = 1.25 MiB

    normalize_cue<<<B * K, 256, 0, stream>>>(cue, cue_n);
    sims_kernel<<<(B * N) / 8, 256, 0, stream>>>(patches, cue_n, sims);
    argmax_gather<<<B * K, 256, 0, stream>>>(sims, patches, out);
}

// Round 3
// 362.777 us; speedup vs baseline: 1.0628x; 1.0057x over previous
//
#include <hip/hip_runtime.h>
#include <math.h>

#define B 64
#define K 5
#define D 1024
#define H 32
#define W 32
#define N (H * W)

__device__ __forceinline__ float wave_sum(float v) {
#pragma unroll
    for (int off = 32; off > 0; off >>= 1) v += __shfl_down(v, off, 64);
    return v;
}

__device__ __forceinline__ float dot4(float4 a, float4 b) {
    return a.x * b.x + a.y * b.y + a.z * b.z + a.w * b.w;
}

// One block per cue row (b*K+k). 256 threads x float4 covers D=1024.
__global__ __launch_bounds__(256) void normalize_cue(const float* __restrict__ cue,
                                                     float* __restrict__ cue_n) {
    const int row = blockIdx.x;
    const int tid = threadIdx.x;
    const float4* src = (const float4*)(cue + (size_t)row * D);
    float4 p = src[tid];
    float ss = p.x * p.x + p.y * p.y + p.z * p.z + p.w * p.w;
    ss = wave_sum(ss);
    __shared__ float smem[4];
    __shared__ float s_inv;
    const int lane = tid & 63, wid = tid >> 6;
    if (lane == 0) smem[wid] = ss;
    __syncthreads();
    if (tid == 0) {
        float t = smem[0] + smem[1] + smem[2] + smem[3];
        s_inv = 1.0f / fmaxf(sqrtf(t), 1e-12f);
    }
    __syncthreads();
    const float inv = s_inv;
    float4 o = make_float4(p.x * inv, p.y * inv, p.z * inv, p.w * inv);
    ((float4*)(cue_n + (size_t)row * D))[tid] = o;
}

// One WAVE per 4 patch rows; block = 4 waves = 16 rows; grid = B*N/16.
// 24 accumulators/lane (4 rows x (norm + 5 dots)); packed exchange
// reduction: masks {1,2,4} halve the value count (12+6+3 shuffles), then
// masks {8,16,32} fully reduce the remaining 3 (9 shuffles) = 30 DS ops
// per 4 rows (was 36/row). Totals land on lanes 0..7 at
// base = 12*(l&1)+6*((l>>1)&1)+3*((l>>2)&1); staged via a tiny LDS slab.
__global__ __launch_bounds__(256) void sims_kernel(const float* __restrict__ patches,
                                                   const float* __restrict__ cue_n,
                                                   float* __restrict__ sims) {
    const int wave = threadIdx.x >> 6;
    const int lane = threadIdx.x & 63;
    const int bn0 = blockIdx.x * 16 + wave * 4;  // 16 | N so b is block-uniform
    const int b = bn0 >> 10;
    const int n0 = bn0 & (N - 1);

    const float4* prow = (const float4*)(patches + (size_t)bn0 * D);
    const float4* crow = (const float4*)(cue_n + (size_t)b * K * D);

    float acc[24];
#pragma unroll
    for (int v = 0; v < 24; ++v) acc[v] = 0.f;

#pragma unroll
    for (int j = 0; j < 4; ++j) {
        const int idx = j * 64 + lane;  // float4 index within a 256-float4 row
        float4 p[4];
#pragma unroll
        for (int r = 0; r < 4; ++r) p[r] = prow[r * 256 + idx];
#pragma unroll
        for (int r = 0; r < 4; ++r) acc[r * 6] += dot4(p[r], p[r]);
#pragma unroll
        for (int k = 0; k < K; ++k) {
            float4 c = crow[k * 256 + idx];
#pragma unroll
            for (int r = 0; r < 4; ++r) acc[r * 6 + 1 + k] += dot4(p[r], c);
        }
    }

    // --- packed exchange reduction: 24 -> 12 -> 6 -> 3 values/lane ---
#pragma unroll
    for (int i = 0; i < 12; ++i) {
        float t = (lane & 1) ? acc[i] : acc[i + 12];
        float r = __shfl_xor(t, 1, 64);
        acc[i] = ((lane & 1) ? acc[i + 12] : acc[i]) + r;
    }
#pragma unroll
    for (int i = 0; i < 6; ++i) {
        float t = (lane & 2) ? acc[i] : acc[i + 6];
        float r = __shfl_xor(t, 2, 64);
        acc[i] = ((lane & 2) ? acc[i + 6] : acc[i]) + r;
    }
#pragma unroll
    for (int i = 0; i < 3; ++i) {
        float t = (lane & 4) ? acc[i] : acc[i + 3];
        float r = __shfl_xor(t, 4, 64);
        acc[i] = ((lane & 4) ? acc[i + 3] : acc[i]) + r;
    }
    // --- full butterfly on the remaining 3 values ---
#pragma unroll
    for (int m = 8; m <= 32; m <<= 1) {
#pragma unroll
        for (int i = 0; i < 3; ++i) acc[i] += __shfl_xor(acc[i], m, 64);
    }

    __shared__ float slab[4][24];
    if (lane < 8) {
        const int base = 12 * (lane & 1) + 6 * ((lane >> 1) & 1) + 3 * ((lane >> 2) & 1);
        slab[wave][base + 0] = acc[0];
        slab[wave][base + 1] = acc[1];
        slab[wave][base + 2] = acc[2];
    }
    __syncthreads();
    if (lane < 4 * K) {
        const int r = lane / K, k = lane % K;
        const float inv = 1.0f / fmaxf(sqrtf(slab[wave][r * 6]), 1e-12f);
        sims[((size_t)b * K + k) * N + n0 + r] = slab[wave][r * 6 + 1 + k] * inv;
    }
}

// One block per (b, k): argmax over N sims (first-index tie-break),
// then mean of raw patches over the 3x3 zero-padded neighborhood.
__global__ __launch_bounds__(256) void argmax_gather(const float* __restrict__ sims,
                                                     const float* __restrict__ patches,
                                                     float* __restrict__ out) {
    const int row = blockIdx.x;  // b*K + k
    const int b = row / K;
    const int tid = threadIdx.x;

    const float4* srow = (const float4*)(sims + (size_t)row * N);
    float4 v = srow[tid];
    float best = v.x;
    int bidx = tid * 4;
    if (v.y > best) { best = v.y; bidx = tid * 4 + 1; }
    if (v.z > best) { best = v.z; bidx = tid * 4 + 2; }
    if (v.w > best) { best = v.w; bidx = tid * 4 + 3; }
#pragma unroll
    for (int off = 32; off > 0; off >>= 1) {
        const float ov = __shfl_down(best, off, 64);
        const int oi = __shfl_down(bidx, off, 64);
        if (ov > best || (ov == best && oi < bidx)) { best = ov; bidx = oi; }
    }
    __shared__ float sv[4];
    __shared__ int si[4];
    __shared__ int s_final;
    const int lane = tid & 63, wid = tid >> 6;
    if (lane == 0) { sv[wid] = best; si[wid] = bidx; }
    __syncthreads();
    if (tid == 0) {
        float bv = sv[0];
        int bi = si[0];
        for (int w2 = 1; w2 < 4; ++w2) {
            if (sv[w2] > bv || (sv[w2] == bv && si[w2] < bi)) { bv = sv[w2]; bi = si[w2]; }
        }
        s_final = bi;
    }
    __syncthreads();

    const int idx = s_final;
    const int y0 = idx >> 5;   // idx / W
    const int x0 = idx & 31;   // idx % W

    float4 acc = make_float4(0.f, 0.f, 0.f, 0.f);
#pragma unroll
    for (int dy = -1; dy <= 1; ++dy) {
        const int yy = y0 + dy;
        if (yy < 0 || yy >= H) continue;
#pragma unroll
        for (int dx = -1; dx <= 1; ++dx) {
            const int xx = x0 + dx;
            if (xx < 0 || xx >= W) continue;
            const float4* nrow =
                (const float4*)(patches + (((size_t)b * H + yy) * W + xx) * D);
            float4 p = nrow[tid];
            acc.x += p.x; acc.y += p.y; acc.z += p.z; acc.w += p.w;
        }
    }
    const float inv9 = 1.0f / 9.0f;
    float4 o = make_float4(acc.x * inv9, acc.y * inv9, acc.z * inv9, acc.w * inv9);
    ((float4*)(out + (size_t)row * D))[tid] = o;
}

extern "C" void kernel_launch(void* const* d_in, const int* in_sizes, int n_in,
                              void* d_out, int out_size, void* d_ws, size_t ws_size,
                              hipStream_t stream) {
    const float* cue = (const float*)d_in[0];
    const float* patches = (const float*)d_in[1];
    float* out = (float*)d_out;

    float* cue_n = (float*)d_ws;              // B*K*D floats = 1.25 MiB
    float* sims = cue_n + (size_t)B * K * D;  // B*K*N floats = 1.25 MiB

    normalize_cue<<<B * K, 256, 0, stream>>>(cue, cue_n);
    sims_kernel<<<(B * N) / 16, 256, 0, stream>>>(patches, cue_n, sims);
    argmax_gather<<<B * K, 256, 0, stream>>>(sims, patches, out);
}

// Round 4
// 361.471 us; speedup vs baseline: 1.0667x; 1.0036x over previous
//
#include <hip/hip_runtime.h>
#include <math.h>

#define B 64
#define K 5
#define D 1024
#define H 32
#define W 32
#define N (H * W)

typedef unsigned long long u64;
typedef unsigned int u32;

__device__ __forceinline__ float dot4(float4 a, float4 b) {
    return a.x * b.x + a.y * b.y + a.z * b.z + a.w * b.w;
}

// One WAVE per 4 patch rows; block = 4 waves = 16 rows; grid = B*N/16.
// Uses RAW cue (1/||cue|| is a positive per-(b,k) constant -> argmax-invariant).
// 24 accumulators/lane (4 rows x (||p||^2 + 5 dots)); packed exchange
// reduction (masks 1,2,4 halve value count, then full butterfly on 3) =
// 30 DS ops per 4 rows. Argmax is fused: candidates packed as
// (monotone_bits(sim) << 32) | (1023 - n) so u64 max == (max sim, min n),
// matching jnp.argmax first-index tie-break; 5 atomicMax per block.
__global__ __launch_bounds__(256) void sims_argmax(const float* __restrict__ patches,
                                                   const float* __restrict__ cue,
                                                   u64* __restrict__ slots) {
    const int wave = threadIdx.x >> 6;
    const int lane = threadIdx.x & 63;
    const int bn0 = blockIdx.x * 16 + wave * 4;  // 16 | N so b is block-uniform
    const int b = bn0 >> 10;
    const int n0 = bn0 & (N - 1);

    const float4* prow = (const float4*)(patches + (size_t)bn0 * D);
    const float4* crow = (const float4*)(cue + (size_t)b * K * D);

    float acc[24];
#pragma unroll
    for (int v = 0; v < 24; ++v) acc[v] = 0.f;

#pragma unroll
    for (int j = 0; j < 4; ++j) {
        const int idx = j * 64 + lane;  // float4 index within a 256-float4 row
        float4 p[4];
#pragma unroll
        for (int r = 0; r < 4; ++r) p[r] = prow[r * 256 + idx];
#pragma unroll
        for (int r = 0; r < 4; ++r) acc[r * 6] += dot4(p[r], p[r]);
#pragma unroll
        for (int k = 0; k < K; ++k) {
            float4 c = crow[k * 256 + idx];
#pragma unroll
            for (int r = 0; r < 4; ++r) acc[r * 6 + 1 + k] += dot4(p[r], c);
        }
    }

    // --- packed exchange reduction: 24 -> 12 -> 6 -> 3 values/lane ---
#pragma unroll
    for (int i = 0; i < 12; ++i) {
        float t = (lane & 1) ? acc[i] : acc[i + 12];
        float r = __shfl_xor(t, 1, 64);
        acc[i] = ((lane & 1) ? acc[i + 12] : acc[i]) + r;
    }
#pragma unroll
    for (int i = 0; i < 6; ++i) {
        float t = (lane & 2) ? acc[i] : acc[i + 6];
        float r = __shfl_xor(t, 2, 64);
        acc[i] = ((lane & 2) ? acc[i + 6] : acc[i]) + r;
    }
#pragma unroll
    for (int i = 0; i < 3; ++i) {
        float t = (lane & 4) ? acc[i] : acc[i + 3];
        float r = __shfl_xor(t, 4, 64);
        acc[i] = ((lane & 4) ? acc[i + 3] : acc[i]) + r;
    }
#pragma unroll
    for (int m = 8; m <= 32; m <<= 1) {
#pragma unroll
        for (int i = 0; i < 3; ++i) acc[i] += __shfl_xor(acc[i], m, 64);
    }

    __shared__ float slab[4][24];
    __shared__ u64 cand[4][20];
    if (lane < 8) {
        const int base = 12 * (lane & 1) + 6 * ((lane >> 1) & 1) + 3 * ((lane >> 2) & 1);
        slab[wave][base + 0] = acc[0];
        slab[wave][base + 1] = acc[1];
        slab[wave][base + 2] = acc[2];
    }
    __syncthreads();
    if (lane < 4 * K) {
        const int r = lane / K, k = lane % K;
        const float inv = 1.0f / fmaxf(sqrtf(slab[wave][r * 6]), 1e-12f);
        const float s = slab[wave][r * 6 + 1 + k] * inv;
        const u32 bits = __float_as_uint(s);
        const u32 u = bits ^ ((bits & 0x80000000u) ? 0xFFFFFFFFu : 0x80000000u);
        const int n = n0 + r;
        cand[wave][lane] = ((u64)u << 32) | (u32)(N - 1 - n);
    }
    __syncthreads();
    if (threadIdx.x < K) {
        const int k = threadIdx.x;
        u64 best = 0;
#pragma unroll
        for (int w2 = 0; w2 < 4; ++w2)
#pragma unroll
            for (int r = 0; r < 4; ++r) {
                const u64 c = cand[w2][r * K + k];
                if (c > best) best = c;
            }
        atomicMax(&slots[(size_t)b * K + k], best);
    }
}

// One block per (b, k): decode winner index, mean of raw patches over the
// 3x3 zero-padded neighborhood.
__global__ __launch_bounds__(256) void gather_kernel(const u64* __restrict__ slots,
                                                     const float* __restrict__ patches,
                                                     float* __restrict__ out) {
    const int row = blockIdx.x;  // b*K + k
    const int b = row / K;
    const int tid = threadIdx.x;

    const u64 c = slots[row];
    const int idx = (N - 1) - (int)(c & 0xFFFFFFFFull);
    const int y0 = idx >> 5;   // idx / W
    const int x0 = idx & 31;   // idx % W

    float4 acc = make_float4(0.f, 0.f, 0.f, 0.f);
#pragma unroll
    for (int dy = -1; dy <= 1; ++dy) {
        const int yy = y0 + dy;
        if (yy < 0 || yy >= H) continue;
#pragma unroll
        for (int dx = -1; dx <= 1; ++dx) {
            const int xx = x0 + dx;
            if (xx < 0 || xx >= W) continue;
            const float4* nrow =
                (const float4*)(patches + (((size_t)b * H + yy) * W + xx) * D);
            float4 p = nrow[tid];
            acc.x += p.x; acc.y += p.y; acc.z += p.z; acc.w += p.w;
        }
    }
    const float inv9 = 1.0f / 9.0f;
    float4 o = make_float4(acc.x * inv9, acc.y * inv9, acc.z * inv9, acc.w * inv9);
    ((float4*)(out + (size_t)row * D))[tid] = o;
}

extern "C" void kernel_launch(void* const* d_in, const int* in_sizes, int n_in,
                              void* d_out, int out_size, void* d_ws, size_t ws_size,
                              hipStream_t stream) {
    const float* cue = (const float*)d_in[0];
    const float* patches = (const float*)d_in[1];
    float* out = (float*)d_out;

    u64* slots = (u64*)d_ws;  // B*K u64 atomic-argmax slots (2.5 KiB)

    hipMemsetAsync(slots, 0, (size_t)B * K * sizeof(u64), stream);
    sims_argmax<<<(B * N) / 16, 256, 0, stream>>>(patches, cue, slots);
    gather_kernel<<<B * K, 256, 0, stream>>>(slots, patches, out);
}